// Round 8
// baseline (122.751 us; speedup 1.0000x reference)
//
#include <hip/hip_runtime.h>

#define B_ 16
#define L_ 4096
#define DK_ 64
#define R_ 4
#define NB_ 64
#define BL_ 64

typedef __attribute__((ext_vector_type(8))) short bf16x8;
typedef __attribute__((ext_vector_type(4))) float f32x4;

__device__ __forceinline__ float bf2f(unsigned short u) {
  return __uint_as_float(((unsigned)u) << 16);
}
// HW packed f32->bf16 (RNE) — 1 inst per 2 values
__device__ __forceinline__ unsigned cvtpk(float lo, float hi) {
  unsigned r;
  asm("v_cvt_pk_bf16_f32 %0, %1, %2" : "=v"(r) : "v"(lo), "v"(hi));
  return r;
}
__device__ __forceinline__ int swz(int row) { return (row & 7) ^ ((row >> 3) & 7); }

// ---- Kernel 0: rm column inverse norms (fp64, d-ascending order) -----------
__global__ __launch_bounds__(128) void prep_kernel(
    const float* __restrict__ rm, double* __restrict__ sinvd) {
  int b = blockIdx.x;
  int t = threadIdx.x;   // 128 columns
  const float* rb = rm + (size_t)b * (DK_ * 128);
  double ss = 0.0;
  for (int d = 0; d < DK_; ++d) {
    double v = (double)rb[d * 128 + t];
    ss += v * v;
  }
  sinvd[b * 128 + t] = 1.0 / sqrt(ss);
}

// ---- Kernel 1: LSH hashing — fp64 vector, 2x16 register tile (UNCHANGED) ---
__global__ __launch_bounds__(256) void hash_kernel(
    const float* __restrict__ query, const float* __restrict__ rm,
    const double* __restrict__ sinvd, int* __restrict__ bucket) {
  __shared__ float qs[64 * 68];      // q[tok][d], stride 68
  __shared__ float rs[64 * 136];     // rm[d][rn], stride 136
  __shared__ double ssin[128];
  __shared__ int sb[64 * 4];

  int b = blockIdx.x >> 6;
  int tok0 = (blockIdx.x & 63) << 6;   // 64 tokens per block
  int t = threadIdx.x;

  {  // stage q: 64 tok x 16 float4
    const float4* qg = (const float4*)(query + ((size_t)b * L_ + tok0) * DK_);
    #pragma unroll
    for (int u = 0; u < 4; ++u) {
      int i = t + u * 256;
      int tokl = i >> 4, c4 = i & 15;
      *(float4*)(qs + tokl * 68 + c4 * 4) = qg[i];
    }
  }
  {  // stage rm: 64 d x 32 float4
    const float4* rg = (const float4*)(rm + (size_t)b * (DK_ * 128));
    #pragma unroll
    for (int u = 0; u < 8; ++u) {
      int i = t + u * 256;
      int d = i >> 5, c4 = i & 31;
      *(float4*)(rs + d * 136 + c4 * 4) = rg[i];
    }
  }
  if (t < 128) ssin[t] = sinvd[b * 128 + t];
  __syncthreads();

  int cg = t & 7;
  int tg = t >> 3;
  double acc0[16], acc1[16];
  #pragma unroll
  for (int j = 0; j < 16; ++j) { acc0[j] = 0.0; acc1[j] = 0.0; }

  const float* q0 = qs + (tg * 2 + 0) * 68;
  const float* q1 = qs + (tg * 2 + 1) * 68;
  const float* rp = rs + cg * 16;
  for (int d = 0; d < DK_; ++d) {
    double qa = (double)q0[d];
    double qb = (double)q1[d];
    const float* rr = rp + d * 136;
    #pragma unroll
    for (int j4 = 0; j4 < 4; ++j4) {
      float4 rv = *(const float4*)(rr + j4 * 4);
      double r0 = (double)rv.x, r1 = (double)rv.y,
             r2 = (double)rv.z, r3 = (double)rv.w;
      acc0[j4 * 4 + 0] += qa * r0; acc0[j4 * 4 + 1] += qa * r1;
      acc0[j4 * 4 + 2] += qa * r2; acc0[j4 * 4 + 3] += qa * r3;
      acc1[j4 * 4 + 0] += qb * r0; acc1[j4 * 4 + 1] += qb * r1;
      acc1[j4 * 4 + 2] += qb * r2; acc1[j4 * 4 + 3] += qb * r3;
    }
  }

  double bv0 = -1e300, bv1 = -1e300;
  int bi0 = 0, bi1 = 0;
  int nbase = (cg & 1) * 16;
  #pragma unroll
  for (int j = 0; j < 16; ++j) {
    int col = cg * 16 + j;
    double sv = ssin[col];
    int n = nbase + j;
    double v0 = acc0[j] * sv;
    double v1 = acc1[j] * sv;
    if (v0 > bv0 || (v0 == bv0 && n < bi0)) { bv0 = v0; bi0 = n; }
    if (-v0 > bv0 || (-v0 == bv0 && n + 32 < bi0)) { bv0 = -v0; bi0 = n + 32; }
    if (v1 > bv1 || (v1 == bv1 && n < bi1)) { bv1 = v1; bi1 = n; }
    if (-v1 > bv1 || (-v1 == bv1 && n + 32 < bi1)) { bv1 = -v1; bi1 = n + 32; }
  }
  {
    double ov = __shfl_xor(bv0, 1);
    int oi = __shfl_xor(bi0, 1);
    if (ov > bv0 || (ov == bv0 && oi < bi0)) { bv0 = ov; bi0 = oi; }
    ov = __shfl_xor(bv1, 1);
    oi = __shfl_xor(bi1, 1);
    if (ov > bv1 || (ov == bv1 && oi < bi1)) { bv1 = ov; bi1 = oi; }
  }
  if ((cg & 1) == 0) {
    int rr_ = cg >> 1;
    sb[(tg * 2 + 0) * 4 + rr_] = bi0;
    sb[(tg * 2 + 1) * 4 + rr_] = bi1;
  }
  __syncthreads();
  if (t < 64)
    ((int4*)bucket)[(size_t)b * L_ + tok0 + t] = ((int4*)sb)[t];
}

// ------- Kernel 2: 16-wave two-level stable counting sort per (b, r) --------
__global__ __launch_bounds__(1024) void sort_kernel(
    const int* __restrict__ bucket, int* __restrict__ sorted_pos,
    unsigned char* __restrict__ cpack) {
  int b = blockIdx.x >> 2;
  int r = blockIdx.x & 3;
  __shared__ int hist[64 * 65];   // [chunk][bin], stride 65
  __shared__ int off[64];
  int t = threadIdx.x, lane = t & 63, w = t >> 6;
  unsigned long long ltmask = (1ull << lane) - 1ull;
  const int* bb = bucket + (size_t)b * L_ * 4 + r;

  int binv[4], rank[4];
  #pragma unroll
  for (int u = 0; u < 4; ++u)
    binv[u] = bb[(size_t)((w * 4 + u) * 64 + lane) * 4];

  for (int idx = t; idx < 64 * 65; idx += 1024) hist[idx] = 0;
  __syncthreads();

  #pragma unroll
  for (int u = 0; u < 4; ++u) {
    int bin = binv[u];
    unsigned long long m = ~0ull;
    #pragma unroll
    for (int k = 0; k < 6; ++k) {
      unsigned long long bal = __ballot((bin >> k) & 1);
      m &= ((bin >> k) & 1) ? bal : ~bal;
    }
    rank[u] = (int)__popcll(m & ltmask);
    if (rank[u] == 0) hist[(w * 4 + u) * 65 + bin] = (int)__popcll(m);
  }
  __syncthreads();

  if (w == 0) {
    int run = 0;
    for (int g = 0; g < 64; ++g) {
      int v = hist[g * 65 + lane];
      hist[g * 65 + lane] = run;
      run += v;
    }
    int inc = run;
    #pragma unroll
    for (int d = 1; d < 64; d <<= 1) {
      int y = __shfl_up(inc, d, 64);
      if (lane >= d) inc += y;
    }
    off[lane] = inc - run;
  }
  __syncthreads();

  int* sp = sorted_pos + ((size_t)b * R_ + r) * L_;
  unsigned char* cp = cpack + (size_t)b * L_ * 4 + r;
  #pragma unroll
  for (int u = 0; u < 4; ++u) {
    int g = w * 4 + u;
    int bin = binv[u];
    int slot = off[bin] + hist[g * 65 + bin] + rank[u];
    sp[slot] = g * 64 + lane;
    cp[(size_t)(g * 64 + lane) * 4] = (unsigned char)(slot >> 6);
  }
}

// ---------------- Kernel 3: per-chunk attention (bf16 MFMA) ------------------
// QK^T: A = normalized q rows from bufK. PV transposed: O^T = (VT as A)(P^T as B)
// so the P write side is vectorized (ds_write_b64) and att scatter is 8B stores.
__global__ __launch_bounds__(256) void attn_kernel(
    const float* __restrict__ query, const float* __restrict__ value,
    const int* __restrict__ sorted_pos, const int* __restrict__ bucket,
    const int* __restrict__ cpack,
    unsigned short* __restrict__ att, float* __restrict__ lse_s) {
  int wg = (int)blockIdx.x;
  wg = (wg & 7) * (B_ * R_ * NB_ / 8) + (wg >> 3);   // XCD-contiguous swizzle
  int n = wg & 63;
  int r = (wg >> 6) & 3;
  int b = wg >> 8;

  __shared__ __align__(16) short bufK[128 * 64];       // K_norm bf16; reused as VT[64][128]
  __shared__ __align__(16) unsigned short ptb[4 * 2560]; // P^T per wave: [128 k][16 q] stride 20
  __shared__ float ssca[64];                           // 0.125*log2e*|q_i|
  __shared__ int skpos[128];
  __shared__ int sbk[128];
  __shared__ int sckp[128];

  int t = threadIdx.x;
  const int* sp = sorted_pos + ((size_t)b * R_ + r) * L_;

  if (t < 128) {
    int chunk = (t < 64) ? ((n + 63) & 63) : n;
    int pos = sp[chunk * 64 + (t & 63)];
    skpos[t] = pos;
    sbk[t] = bucket[((size_t)b * L_ + pos) * 4 + r];
    sckp[t] = ((const int*)cpack)[(size_t)b * L_ + pos];
  }
  __syncthreads();

  // ---- stage K_norm (bf16, swizzled) + per-row scale for query rows ----
  {
    int j = t >> 1, half = t & 1;
    const float* qr = query + ((size_t)b * L_ + skpos[j]) * DK_ + half * 32;
    float v[32];
    float ss = 0.f;
    #pragma unroll
    for (int u = 0; u < 8; ++u) {
      float4 x = ((const float4*)qr)[u];
      v[u*4+0] = x.x; v[u*4+1] = x.y; v[u*4+2] = x.z; v[u*4+3] = x.w;
      ss += x.x*x.x + x.y*x.y + x.z*x.z + x.w*x.w;
    }
    ss += __shfl_xor(ss, 1);
    float inv = 1.0f / fmaxf(sqrtf(ss), 1e-12f);
    short* krow = bufK + j * 64;
    #pragma unroll
    for (int u = 0; u < 4; ++u) {
      int d0 = half * 32 + u * 8;
      uint4 pk;
      pk.x = cvtpk(v[u*8+0] * inv, v[u*8+1] * inv);
      pk.y = cvtpk(v[u*8+2] * inv, v[u*8+3] * inv);
      pk.z = cvtpk(v[u*8+4] * inv, v[u*8+5] * inv);
      pk.w = cvtpk(v[u*8+6] * inv, v[u*8+7] * inv);
      *(uint4*)(krow + (((d0 >> 3) ^ swz(j)) << 3)) = pk;
    }
    if (j >= 64 && half == 0) ssca[j - 64] = 0.18033688f / inv;  // 0.125*log2e*|q|
  }
  __syncthreads();

  int l = t & 63, w = t >> 6;
  // ---- QK^T via MFMA: A = normalized q rows (bufK rows 64..127) ----
  f32x4 acc[8];
  #pragma unroll
  for (int tt = 0; tt < 8; ++tt) acc[tt] = (f32x4){0.f, 0.f, 0.f, 0.f};
  {
    int qrow = 64 + w * 16 + (l & 15);
    const short* qp_ = bufK + qrow * 64;
    bf16x8 a0 = *(const bf16x8*)(qp_ + ((((l >> 4)) ^ swz(qrow)) << 3));
    bf16x8 a1 = *(const bf16x8*)(qp_ + (((4 + (l >> 4)) ^ swz(qrow)) << 3));
    #pragma unroll
    for (int tt = 0; tt < 8; ++tt) {
      int krow = tt * 16 + (l & 15);
      const short* kp_ = bufK + krow * 64;
      bf16x8 b0 = *(const bf16x8*)(kp_ + ((((l >> 4)) ^ swz(krow)) << 3));
      bf16x8 b1 = *(const bf16x8*)(kp_ + (((4 + (l >> 4)) ^ swz(krow)) << 3));
      acc[tt] = __builtin_amdgcn_mfma_f32_16x16x32_bf16(a0, b0, acc[tt], 0, 0, 0);
      acc[tt] = __builtin_amdgcn_mfma_f32_16x16x32_bf16(a1, b1, acc[tt], 0, 0, 0);
    }
  }
  __syncthreads();   // all waves done reading bufK

  // ---- issue V loads early (latency hides under softmax VALU) ----
  int pi = t >> 2, qd = t & 3;
  const float* vr0 = value + ((size_t)b * L_ + skpos[2 * pi]) * DK_ + qd * 16;
  const float* vr1 = value + ((size_t)b * L_ + skpos[2 * pi + 1]) * DK_ + qd * 16;
  float4 va[4], vb4[4];
  #pragma unroll
  for (int c4 = 0; c4 < 4; ++c4) { va[c4] = ((const float4*)vr0)[c4]; vb4[c4] = ((const float4*)vr1)[c4]; }

  // ---- masks + softmax (exp2 domain), in registers on the MFMA D-layout ----
  int kp[8], bk[8], ck[8];
  #pragma unroll
  for (int tt = 0; tt < 8; ++tt) {
    int col = tt * 16 + (l & 15);
    kp[tt] = skpos[col]; bk[tt] = sbk[col]; ck[tt] = sckp[col];
  }
  float st[8][4];
  float lse[4], psum[4];
  int qprow[4];
  #pragma unroll
  for (int j = 0; j < 4; ++j) {
    int qrow = w * 16 + (l >> 4) * 4 + j;
    int qp2 = skpos[64 + qrow];
    int bq = sbk[64 + qrow];
    float csc = ssca[qrow];
    qprow[j] = qp2;
    #pragma unroll
    for (int tt = 0; tt < 8; ++tt) {
      float s = acc[tt][j] * csc;
      s = ((qp2 < kp[tt]) || (bq != bk[tt])) ? -1e9f : s;
      s = (qp2 == kp[tt]) ? -144269.5f : s;   // -1e5 * log2e
      st[tt][j] = s;
    }
    float m = st[0][j];
    #pragma unroll
    for (int tt = 1; tt < 8; ++tt) m = fmaxf(m, st[tt][j]);
    m = fmaxf(m, __shfl_xor(m, 1));
    m = fmaxf(m, __shfl_xor(m, 2));
    m = fmaxf(m, __shfl_xor(m, 4));
    m = fmaxf(m, __shfl_xor(m, 8));
    float sum = 0.f;
    #pragma unroll
    for (int tt = 0; tt < 8; ++tt) { float e = exp2f(st[tt][j] - m); st[tt][j] = e; sum += e; }
    sum += __shfl_xor(sum, 1);
    sum += __shfl_xor(sum, 2);
    sum += __shfl_xor(sum, 4);
    sum += __shfl_xor(sum, 8);
    psum[j] = sum;
    lse[j] = 0.69314718f * (m + __log2f(sum));
  }

  // ---- dup-count (SWAR) -> final P (in st) ----
  #pragma unroll
  for (int j = 0; j < 4; ++j) {
    int qrow = w * 16 + (l >> 4) * 4 + j;
    unsigned aq = (unsigned)sckp[64 + qrow] | 0x40404040u;
    float isum = 1.0f / psum[j];
    #pragma unroll
    for (int tt = 0; tt < 8; ++tt) {
      unsigned e = (aq - (unsigned)ck[tt]) & 0x3E3E3E3Eu;
      unsigned y = (e - 0x01010101u) & ~e & 0x80808080u;
      float cntf = (float)__popc(y);
      st[tt][j] = st[tt][j] * isum * __builtin_amdgcn_rcpf(cntf);
    }
  }
  if ((l & 15) == 0) {
    #pragma unroll
    for (int j = 0; j < 4; ++j)
      lse_s[((size_t)b * R_ + r) * L_ + qprow[j]] = lse[j];
  }

  // ---- P^T -> LDS (wave-local): rows k, cols q (4 adjacent per write) ----
  {
    unsigned short* PT = ptb + w * 2560;
    int q0 = (l >> 4) * 4;
    #pragma unroll
    for (int tt = 0; tt < 8; ++tt) {
      unsigned u0 = cvtpk(st[tt][0], st[tt][1]);
      unsigned u1 = cvtpk(st[tt][2], st[tt][3]);
      int krow = tt * 16 + (l & 15);
      *(uint2*)(PT + krow * 20 + q0) = make_uint2(u0, u1);
    }
  }

  // ---- VT staging into freed bufK: VT[d][k] packed pairs along k ----
  short* VT = bufK;
  #pragma unroll
  for (int c4 = 0; c4 < 4; ++c4) {
    float4 x0 = va[c4], x1 = vb4[c4];
    #pragma unroll
    for (int cc = 0; cc < 4; ++cc) {
      float f0 = (cc == 0) ? x0.x : (cc == 1) ? x0.y : (cc == 2) ? x0.z : x0.w;
      float f1 = (cc == 0) ? x1.x : (cc == 1) ? x1.y : (cc == 2) ? x1.z : x1.w;
      unsigned pk2 = cvtpk(f0, f1);
      int nrow = qd * 16 + c4 * 4 + cc;
      int k0 = 2 * pi;
      int a = nrow * 128 + (((k0 >> 3) ^ swz(nrow)) << 3) + (k0 & 7);
      *(unsigned*)(VT + a) = pk2;
    }
  }
  __syncthreads();

  // ---- PV via MFMA, transposed: O^T[d][q] = sum_k VT[d][k] * P^T[k][q] ----
  f32x4 o[4];
  #pragma unroll
  for (int nt = 0; nt < 4; ++nt) o[nt] = (f32x4){0.f, 0.f, 0.f, 0.f};
  {
    const unsigned short* PTr = ptb + w * 2560;
    #pragma unroll
    for (int ks = 0; ks < 4; ++ks) {
      int basePT = (ks * 32 + (l >> 4) * 8) * 20 + (l & 15);
      union { uint4 u; bf16x8 v; } bp;
      bp.u.x = (unsigned)PTr[basePT]       | ((unsigned)PTr[basePT + 20] << 16);
      bp.u.y = (unsigned)PTr[basePT + 40]  | ((unsigned)PTr[basePT + 60] << 16);
      bp.u.z = (unsigned)PTr[basePT + 80]  | ((unsigned)PTr[basePT + 100] << 16);
      bp.u.w = (unsigned)PTr[basePT + 120] | ((unsigned)PTr[basePT + 140] << 16);
      #pragma unroll
      for (int nt = 0; nt < 4; ++nt) {
        int vrow = nt * 16 + (l & 15);
        bf16x8 av = *(const bf16x8*)(VT + vrow * 128 + (((ks * 4 + (l >> 4)) ^ swz(vrow)) << 3));
        o[nt] = __builtin_amdgcn_mfma_f32_16x16x32_bf16(av, bp.v, o[nt], 0, 0, 0);
      }
    }
  }

  // ---- scatter att rows (bf16, 8B stores): thread owns one q-row ----
  {
    int qpos = skpos[64 + w * 16 + (l & 15)];
    unsigned short* arow = att + (((size_t)b * R_ + r) * L_ + qpos) * DK_;
    #pragma unroll
    for (int nt = 0; nt < 4; ++nt) {
      unsigned p0 = cvtpk(o[nt][0], o[nt][1]);
      unsigned p1 = cvtpk(o[nt][2], o[nt][3]);
      *(uint2*)(arow + nt * 16 + (l >> 4) * 4) = make_uint2(p0, p1);
    }
  }
}

// ---------------- Kernel 4: softmax reduction over L of lse ------------------
__global__ __launch_bounds__(256) void lsered_kernel(
    const float* __restrict__ lse_s, float* __restrict__ wred) {
  int br = blockIdx.x;
  const float* row = lse_s + (size_t)br * L_;
  __shared__ float red[4];
  int t = threadIdx.x;
  float m = -1e30f;
  for (int p = t; p < L_; p += 256) m = fmaxf(m, row[p]);
  #pragma unroll
  for (int mask = 1; mask < 64; mask <<= 1) m = fmaxf(m, __shfl_xor(m, mask, 64));
  if ((t & 63) == 0) red[t >> 6] = m;
  __syncthreads();
  m = fmaxf(fmaxf(red[0], red[1]), fmaxf(red[2], red[3]));
  __syncthreads();
  float sum = 0.f;
  for (int p = t; p < L_; p += 256) sum += __expf(row[p] - m);
  #pragma unroll
  for (int mask = 1; mask < 64; mask <<= 1) sum += __shfl_xor(sum, mask, 64);
  if ((t & 63) == 0) red[t >> 6] = sum;
  __syncthreads();
  if (t == 0) {
    wred[br * 2] = m;
    wred[br * 2 + 1] = red[0] + red[1] + red[2] + red[3];
  }
}

// ---------------- Kernel 5: weighted combine over rounds ---------------------
// thread owns (b, l, quarter of d): lse/w computed once per thread for 4 float4s
__global__ __launch_bounds__(256) void combine_kernel(
    const unsigned short* __restrict__ att, const float* __restrict__ lse_s,
    const float* __restrict__ wred, float* __restrict__ out) {
  int idx = blockIdx.x * 256 + threadIdx.x;
  int dq = idx & 3;
  int l = (idx >> 2) & (L_ - 1);
  int b = idx >> 14;
  float wv[4];
  #pragma unroll
  for (int r = 0; r < R_; ++r) {
    float m = wred[(b * R_ + r) * 2];
    float sinv = 1.0f / wred[(b * R_ + r) * 2 + 1];
    wv[r] = __expf(lse_s[((size_t)b * R_ + r) * L_ + l] - m) * sinv;
  }
  #pragma unroll
  for (int u = 0; u < 4; ++u) {
    int d4 = dq * 4 + u;
    float4 o = make_float4(0.f, 0.f, 0.f, 0.f);
    #pragma unroll
    for (int r = 0; r < R_; ++r) {
      ushort4 a = *(const ushort4*)(att + ((((size_t)b * R_ + r) * L_ + l) * 16 + d4) * 4);
      o.x += wv[r] * bf2f(a.x); o.y += wv[r] * bf2f(a.y);
      o.z += wv[r] * bf2f(a.z); o.w += wv[r] * bf2f(a.w);
    }
    ((float4*)out)[((size_t)b * L_ + l) * 16 + d4] = o;
  }
}

extern "C" void kernel_launch(void* const* d_in, const int* in_sizes, int n_in,
                              void* d_out, int out_size, void* d_ws, size_t ws_size,
                              hipStream_t stream) {
  const float* query = (const float*)d_in[0];
  const float* value = (const float*)d_in[1];
  const float* rm    = (const float*)d_in[2];
  (void)in_sizes; (void)n_in; (void)out_size; (void)ws_size;

  char* ws = (char*)d_ws;
  const size_t ATT_BYTES = (size_t)B_ * R_ * L_ * DK_ * 2;  // 32 MiB (bf16)
  const size_t MB = 1048576;
  unsigned short* att        = (unsigned short*)ws;
  int*            bucket     = (int*)(ws + ATT_BYTES);
  int*            sorted_pos = (int*)(ws + ATT_BYTES + 1 * MB);
  unsigned char*  cpack      = (unsigned char*)(ws + ATT_BYTES + 2 * MB);
  float*          lse_s      = (float*)(ws + ATT_BYTES + 3 * MB);
  float*          wred       = (float*)(ws + ATT_BYTES + 4 * MB);
  double*         sinvd      = (double*)(ws + ATT_BYTES + 5 * MB);
  float* out = (float*)d_out;

  prep_kernel<<<B_, 128, 0, stream>>>(rm, sinvd);
  hash_kernel<<<B_ * 64, 256, 0, stream>>>(query, rm, sinvd, bucket);
  sort_kernel<<<B_ * R_, 1024, 0, stream>>>(bucket, sorted_pos, cpack);
  attn_kernel<<<B_ * R_ * NB_, 256, 0, stream>>>(query, value, sorted_pos, bucket,
                                                 (const int*)cpack, att, lse_s);
  lsered_kernel<<<B_ * R_, 256, 0, stream>>>(lse_s, wred);
  combine_kernel<<<(B_ * L_ * 4) / 256, 256, 0, stream>>>(att, lse_s, wred, out);
}

// Round 9
// 120.755 us; speedup vs baseline: 1.0165x; 1.0165x over previous
//
#include <hip/hip_runtime.h>

#define B_ 16
#define L_ 4096
#define DK_ 64
#define R_ 4
#define NB_ 64
#define BL_ 64

typedef __attribute__((ext_vector_type(8))) short bf16x8;
typedef __attribute__((ext_vector_type(4))) float f32x4;

__device__ __forceinline__ float bf2f(unsigned short u) {
  return __uint_as_float(((unsigned)u) << 16);
}
// HW packed f32->bf16 (RNE) — 1 inst per 2 values
__device__ __forceinline__ unsigned cvtpk(float lo, float hi) {
  unsigned r;
  asm("v_cvt_pk_bf16_f32 %0, %1, %2" : "=v"(r) : "v"(lo), "v"(hi));
  return r;
}
__device__ __forceinline__ int swz(int row) { return (row & 7) ^ ((row >> 3) & 7); }

// ---- Kernel 0: rm column inverse norms (fp64, d-ascending order) -----------
__global__ __launch_bounds__(128) void prep_kernel(
    const float* __restrict__ rm, double* __restrict__ sinvd) {
  int b = blockIdx.x;
  int t = threadIdx.x;   // 128 columns
  const float* rb = rm + (size_t)b * (DK_ * 128);
  double ss = 0.0;
  for (int d = 0; d < DK_; ++d) {
    double v = (double)rb[d * 128 + t];
    ss += v * v;
  }
  sinvd[b * 128 + t] = 1.0 / sqrt(ss);
}

// ---- Kernel 1: LSH hashing — fp64 vector, 2x16 register tile (UNCHANGED) ---
__global__ __launch_bounds__(256) void hash_kernel(
    const float* __restrict__ query, const float* __restrict__ rm,
    const double* __restrict__ sinvd, int* __restrict__ bucket) {
  __shared__ float qs[64 * 68];      // q[tok][d], stride 68
  __shared__ float rs[64 * 136];     // rm[d][rn], stride 136
  __shared__ double ssin[128];
  __shared__ int sb[64 * 4];

  int b = blockIdx.x >> 6;
  int tok0 = (blockIdx.x & 63) << 6;   // 64 tokens per block
  int t = threadIdx.x;

  {  // stage q: 64 tok x 16 float4
    const float4* qg = (const float4*)(query + ((size_t)b * L_ + tok0) * DK_);
    #pragma unroll
    for (int u = 0; u < 4; ++u) {
      int i = t + u * 256;
      int tokl = i >> 4, c4 = i & 15;
      *(float4*)(qs + tokl * 68 + c4 * 4) = qg[i];
    }
  }
  {  // stage rm: 64 d x 32 float4
    const float4* rg = (const float4*)(rm + (size_t)b * (DK_ * 128));
    #pragma unroll
    for (int u = 0; u < 8; ++u) {
      int i = t + u * 256;
      int d = i >> 5, c4 = i & 31;
      *(float4*)(rs + d * 136 + c4 * 4) = rg[i];
    }
  }
  if (t < 128) ssin[t] = sinvd[b * 128 + t];
  __syncthreads();

  int cg = t & 7;
  int tg = t >> 3;
  double acc0[16], acc1[16];
  #pragma unroll
  for (int j = 0; j < 16; ++j) { acc0[j] = 0.0; acc1[j] = 0.0; }

  const float* q0 = qs + (tg * 2 + 0) * 68;
  const float* q1 = qs + (tg * 2 + 1) * 68;
  const float* rp = rs + cg * 16;
  for (int d = 0; d < DK_; ++d) {
    double qa = (double)q0[d];
    double qb = (double)q1[d];
    const float* rr = rp + d * 136;
    #pragma unroll
    for (int j4 = 0; j4 < 4; ++j4) {
      float4 rv = *(const float4*)(rr + j4 * 4);
      double r0 = (double)rv.x, r1 = (double)rv.y,
             r2 = (double)rv.z, r3 = (double)rv.w;
      acc0[j4 * 4 + 0] += qa * r0; acc0[j4 * 4 + 1] += qa * r1;
      acc0[j4 * 4 + 2] += qa * r2; acc0[j4 * 4 + 3] += qa * r3;
      acc1[j4 * 4 + 0] += qb * r0; acc1[j4 * 4 + 1] += qb * r1;
      acc1[j4 * 4 + 2] += qb * r2; acc1[j4 * 4 + 3] += qb * r3;
    }
  }

  double bv0 = -1e300, bv1 = -1e300;
  int bi0 = 0, bi1 = 0;
  int nbase = (cg & 1) * 16;
  #pragma unroll
  for (int j = 0; j < 16; ++j) {
    int col = cg * 16 + j;
    double sv = ssin[col];
    int n = nbase + j;
    double v0 = acc0[j] * sv;
    double v1 = acc1[j] * sv;
    if (v0 > bv0 || (v0 == bv0 && n < bi0)) { bv0 = v0; bi0 = n; }
    if (-v0 > bv0 || (-v0 == bv0 && n + 32 < bi0)) { bv0 = -v0; bi0 = n + 32; }
    if (v1 > bv1 || (v1 == bv1 && n < bi1)) { bv1 = v1; bi1 = n; }
    if (-v1 > bv1 || (-v1 == bv1 && n + 32 < bi1)) { bv1 = -v1; bi1 = n + 32; }
  }
  {
    double ov = __shfl_xor(bv0, 1);
    int oi = __shfl_xor(bi0, 1);
    if (ov > bv0 || (ov == bv0 && oi < bi0)) { bv0 = ov; bi0 = oi; }
    ov = __shfl_xor(bv1, 1);
    oi = __shfl_xor(bi1, 1);
    if (ov > bv1 || (ov == bv1 && oi < bi1)) { bv1 = ov; bi1 = oi; }
  }
  if ((cg & 1) == 0) {
    int rr_ = cg >> 1;
    sb[(tg * 2 + 0) * 4 + rr_] = bi0;
    sb[(tg * 2 + 1) * 4 + rr_] = bi1;
  }
  __syncthreads();
  if (t < 64)
    ((int4*)bucket)[(size_t)b * L_ + tok0 + t] = ((int4*)sb)[t];
}

// ------- Kernel 2: 16-wave two-level stable counting sort per (b, r) --------
__global__ __launch_bounds__(1024) void sort_kernel(
    const int* __restrict__ bucket, int* __restrict__ sorted_pos,
    unsigned char* __restrict__ cpack) {
  int b = blockIdx.x >> 2;
  int r = blockIdx.x & 3;
  __shared__ int hist[64 * 65];   // [chunk][bin], stride 65
  __shared__ int off[64];
  int t = threadIdx.x, lane = t & 63, w = t >> 6;
  unsigned long long ltmask = (1ull << lane) - 1ull;
  const int* bb = bucket + (size_t)b * L_ * 4 + r;

  int binv[4], rank[4];
  #pragma unroll
  for (int u = 0; u < 4; ++u)
    binv[u] = bb[(size_t)((w * 4 + u) * 64 + lane) * 4];

  for (int idx = t; idx < 64 * 65; idx += 1024) hist[idx] = 0;
  __syncthreads();

  #pragma unroll
  for (int u = 0; u < 4; ++u) {
    int bin = binv[u];
    unsigned long long m = ~0ull;
    #pragma unroll
    for (int k = 0; k < 6; ++k) {
      unsigned long long bal = __ballot((bin >> k) & 1);
      m &= ((bin >> k) & 1) ? bal : ~bal;
    }
    rank[u] = (int)__popcll(m & ltmask);
    if (rank[u] == 0) hist[(w * 4 + u) * 65 + bin] = (int)__popcll(m);
  }
  __syncthreads();

  if (w == 0) {
    int run = 0;
    for (int g = 0; g < 64; ++g) {
      int v = hist[g * 65 + lane];
      hist[g * 65 + lane] = run;
      run += v;
    }
    int inc = run;
    #pragma unroll
    for (int d = 1; d < 64; d <<= 1) {
      int y = __shfl_up(inc, d, 64);
      if (lane >= d) inc += y;
    }
    off[lane] = inc - run;
  }
  __syncthreads();

  int* sp = sorted_pos + ((size_t)b * R_ + r) * L_;
  unsigned char* cp = cpack + (size_t)b * L_ * 4 + r;
  #pragma unroll
  for (int u = 0; u < 4; ++u) {
    int g = w * 4 + u;
    int bin = binv[u];
    int slot = off[bin] + hist[g * 65 + bin] + rank[u];
    sp[slot] = g * 64 + lane;
    cp[(size_t)(g * 64 + lane) * 4] = (unsigned char)(slot >> 6);
  }
}

// ---------------- Kernel 3: per-chunk attention (bf16 MFMA) ------------------
// Swapped QK^T (S^T = K·Q^T): each lane owns ONE q-row x 32 k's -> lane-local
// softmax; P stays in registers; PV B-frag assembled via __shfl (no P in LDS).
__global__ __launch_bounds__(256) void attn_kernel(
    const float* __restrict__ query, const float* __restrict__ value,
    const int* __restrict__ sorted_pos, const int* __restrict__ bucket,
    const int* __restrict__ cpack,
    unsigned short* __restrict__ att, float* __restrict__ lse_s) {
  int wg = (int)blockIdx.x;
  wg = (wg & 7) * (B_ * R_ * NB_ / 8) + (wg >> 3);   // XCD-contiguous swizzle
  int n = wg & 63;
  int r = (wg >> 6) & 3;
  int b = wg >> 8;

  __shared__ __align__(16) short bufK[128 * 64];   // K_norm bf16; reused as VT[64][128]
  __shared__ float ssca[64];                       // 0.125*log2e*|q_i|
  __shared__ int skpos[128];                       // positions (staging gather)
  __shared__ int skcode[128];                      // (bucket<<12) | pos
  __shared__ int sck[128];                         // packed chunk ids (4x8b)

  int t = threadIdx.x;
  const int* sp = sorted_pos + ((size_t)b * R_ + r) * L_;

  if (t < 128) {
    int chunk = (t < 64) ? ((n + 63) & 63) : n;
    int pos = sp[chunk * 64 + (t & 63)];
    int bkt = bucket[((size_t)b * L_ + pos) * 4 + r];
    skpos[t] = pos;
    skcode[t] = (bkt << 12) | pos;
    sck[t] = ((const int*)cpack)[(size_t)b * L_ + pos];
  }
  __syncthreads();

  // ---- stage K_norm (bf16, swizzled) + per-row scale for query rows ----
  {
    int j = t >> 1, half = t & 1;
    const float* qr = query + ((size_t)b * L_ + skpos[j]) * DK_ + half * 32;
    float v[32];
    float ss = 0.f;
    #pragma unroll
    for (int u = 0; u < 8; ++u) {
      float4 x = ((const float4*)qr)[u];
      v[u*4+0] = x.x; v[u*4+1] = x.y; v[u*4+2] = x.z; v[u*4+3] = x.w;
      ss += x.x*x.x + x.y*x.y + x.z*x.z + x.w*x.w;
    }
    ss += __shfl_xor(ss, 1);
    float inv = 1.0f / fmaxf(sqrtf(ss), 1e-12f);
    short* krow = bufK + j * 64;
    #pragma unroll
    for (int u = 0; u < 4; ++u) {
      int d0 = half * 32 + u * 8;
      uint4 pk;
      pk.x = cvtpk(v[u*8+0] * inv, v[u*8+1] * inv);
      pk.y = cvtpk(v[u*8+2] * inv, v[u*8+3] * inv);
      pk.z = cvtpk(v[u*8+4] * inv, v[u*8+5] * inv);
      pk.w = cvtpk(v[u*8+6] * inv, v[u*8+7] * inv);
      *(uint4*)(krow + (((d0 >> 3) ^ swz(j)) << 3)) = pk;
    }
    if (j >= 64 && half == 0) ssca[j - 64] = 0.18033688f / inv;  // 0.125*log2e*|q|
  }
  __syncthreads();

  int l = t & 63, w = t >> 6;
  int g = l >> 4, c = l & 15;
  // ---- QK^T via MFMA, SWAPPED: D = K_frag · Q_frag = S^T ----
  // acc[tt][j]: k = tt*16 + g*4 + j, q = w*16 + c (one q-row per lane)
  f32x4 acc[8];
  #pragma unroll
  for (int tt = 0; tt < 8; ++tt) acc[tt] = (f32x4){0.f, 0.f, 0.f, 0.f};
  {
    int qrow = 64 + w * 16 + c;
    const short* qp_ = bufK + qrow * 64;
    bf16x8 q0 = *(const bf16x8*)(qp_ + (((g) ^ swz(qrow)) << 3));
    bf16x8 q1 = *(const bf16x8*)(qp_ + (((4 + g) ^ swz(qrow)) << 3));
    #pragma unroll
    for (int tt = 0; tt < 8; ++tt) {
      int krow = tt * 16 + c;
      const short* kp_ = bufK + krow * 64;
      bf16x8 k0 = *(const bf16x8*)(kp_ + (((g) ^ swz(krow)) << 3));
      bf16x8 k1 = *(const bf16x8*)(kp_ + (((4 + g) ^ swz(krow)) << 3));
      acc[tt] = __builtin_amdgcn_mfma_f32_16x16x32_bf16(k0, q0, acc[tt], 0, 0, 0);
      acc[tt] = __builtin_amdgcn_mfma_f32_16x16x32_bf16(k1, q1, acc[tt], 0, 0, 0);
    }
  }
  __syncthreads();   // all waves done reading bufK

  // ---- issue V loads early (latency hides under softmax VALU) ----
  int pi = t >> 2, qd = t & 3;
  const float* vr0 = value + ((size_t)b * L_ + skpos[2 * pi]) * DK_ + qd * 16;
  const float* vr1 = value + ((size_t)b * L_ + skpos[2 * pi + 1]) * DK_ + qd * 16;
  float4 va[4], vb4[4];
  #pragma unroll
  for (int c4 = 0; c4 < 4; ++c4) { va[c4] = ((const float4*)vr0)[c4]; vb4[c4] = ((const float4*)vr1)[c4]; }

  // ---- masks + lane-local softmax (exp2 domain) ----
  int qi = w * 16 + c;
  int qcode = skcode[64 + qi];
  unsigned aq = (unsigned)sck[64 + qi] | 0x40404040u;
  float csc = ssca[qi];
  int qpos = qcode & 4095;

  float m = -1e30f;
  #pragma unroll
  for (int tt = 0; tt < 8; ++tt) {
    int4 kc = *(const int4*)(skcode + tt * 16 + g * 4);
    #pragma unroll
    for (int j = 0; j < 4; ++j) {
      int kcode = (j == 0) ? kc.x : (j == 1) ? kc.y : (j == 2) ? kc.z : kc.w;
      float s = acc[tt][j] * csc;
      unsigned x = (unsigned)(qcode ^ kcode);
      s = ((qcode < kcode) || (x >= 4096u)) ? -1e9f : s;
      s = (x == 0u) ? -144269.5f : s;   // -1e5 * log2e
      acc[tt][j] = s;
      m = fmaxf(m, s);
    }
  }
  m = fmaxf(m, __shfl_xor(m, 16));
  m = fmaxf(m, __shfl_xor(m, 32));
  float sum = 0.f;
  #pragma unroll
  for (int tt = 0; tt < 8; ++tt) {
    #pragma unroll
    for (int j = 0; j < 4; ++j) {
      float e = exp2f(acc[tt][j] - m);
      acc[tt][j] = e;
      sum += e;
    }
  }
  sum += __shfl_xor(sum, 16);
  sum += __shfl_xor(sum, 32);
  float lse = 0.69314718f * (m + __log2f(sum));
  float isum = 1.0f / sum;
  if (l < 16) lse_s[((size_t)b * R_ + r) * L_ + qpos] = lse;

  // ---- dup-count (SWAR) -> final P in registers ----
  #pragma unroll
  for (int tt = 0; tt < 8; ++tt) {
    int4 c4v = *(const int4*)(sck + tt * 16 + g * 4);
    #pragma unroll
    for (int j = 0; j < 4; ++j) {
      int ckv = (j == 0) ? c4v.x : (j == 1) ? c4v.y : (j == 2) ? c4v.z : c4v.w;
      unsigned e = (aq - (unsigned)ckv) & 0x3E3E3E3Eu;
      unsigned y = (e - 0x01010101u) & ~e & 0x80808080u;
      float cntf = (float)__popc(y);
      acc[tt][j] = acc[tt][j] * isum * __builtin_amdgcn_rcpf(cntf);
    }
  }

  // ---- P -> bf16 pairs in registers (per lane: its q-row, k=tt*16+g*4+j) ----
  unsigned pk01[8], pk23[8];
  #pragma unroll
  for (int tt = 0; tt < 8; ++tt) {
    pk01[tt] = cvtpk(acc[tt][0], acc[tt][1]);
    pk23[tt] = cvtpk(acc[tt][2], acc[tt][3]);
  }

  // ---- VT staging into freed bufK: VT[d][k] packed pairs along k ----
  short* VT = bufK;
  #pragma unroll
  for (int c4 = 0; c4 < 4; ++c4) {
    float4 x0 = va[c4], x1 = vb4[c4];
    #pragma unroll
    for (int cc = 0; cc < 4; ++cc) {
      float f0 = (cc == 0) ? x0.x : (cc == 1) ? x0.y : (cc == 2) ? x0.z : x0.w;
      float f1 = (cc == 0) ? x1.x : (cc == 1) ? x1.y : (cc == 2) ? x1.z : x1.w;
      unsigned pk2 = cvtpk(f0, f1);
      int nrow = qd * 16 + c4 * 4 + cc;
      int k0 = 2 * pi;
      int a = nrow * 128 + (((k0 >> 3) ^ swz(nrow)) << 3) + (k0 & 7);
      *(unsigned*)(VT + a) = pk2;
    }
  }
  __syncthreads();

  // ---- PV via MFMA: O^T[d][q] = sum_k VT[d][k] * P^T[k][q] ----
  // B-frag: col=q=c, k-elems g*8+e within ks*32 chunk, gathered via shfl.
  f32x4 o[4];
  #pragma unroll
  for (int nt = 0; nt < 4; ++nt) o[nt] = (f32x4){0.f, 0.f, 0.f, 0.f};
  {
    int src  = (g & 1) * 32 + c;
    int srcB = src + 16;
    bool sel = (l >= 32);
    #pragma unroll
    for (int ks = 0; ks < 4; ++ks) {
      unsigned xA = __shfl(pk01[2 * ks], src),  yA = __shfl(pk01[2 * ks + 1], src);
      unsigned xB = __shfl(pk23[2 * ks], src),  yB = __shfl(pk23[2 * ks + 1], src);
      unsigned xC = __shfl(pk01[2 * ks], srcB), yC = __shfl(pk01[2 * ks + 1], srcB);
      unsigned xD = __shfl(pk23[2 * ks], srcB), yD = __shfl(pk23[2 * ks + 1], srcB);
      union { uint4 u; bf16x8 v; } bp;
      bp.u.x = sel ? yA : xA;
      bp.u.y = sel ? yB : xB;
      bp.u.z = sel ? yC : xC;
      bp.u.w = sel ? yD : xD;
      #pragma unroll
      for (int nt = 0; nt < 4; ++nt) {
        int vrow = nt * 16 + c;
        bf16x8 av = *(const bf16x8*)(VT + vrow * 128 + (((ks * 4 + g) ^ swz(vrow)) << 3));
        o[nt] = __builtin_amdgcn_mfma_f32_16x16x32_bf16(av, bp.v, o[nt], 0, 0, 0);
      }
    }
  }

  // ---- scatter att rows (bf16, 8B stores): lane owns one q-row ----
  {
    unsigned short* arow = att + (((size_t)b * R_ + r) * L_ + qpos) * DK_;
    #pragma unroll
    for (int nt = 0; nt < 4; ++nt) {
      unsigned p0 = cvtpk(o[nt][0], o[nt][1]);
      unsigned p1 = cvtpk(o[nt][2], o[nt][3]);
      *(uint2*)(arow + nt * 16 + g * 4) = make_uint2(p0, p1);
    }
  }
}

// ---------------- Kernel 4: softmax reduction over L of lse ------------------
__global__ __launch_bounds__(256) void lsered_kernel(
    const float* __restrict__ lse_s, float* __restrict__ wred) {
  int br = blockIdx.x;
  const float* row = lse_s + (size_t)br * L_;
  __shared__ float red[4];
  int t = threadIdx.x;
  float m = -1e30f;
  for (int p = t; p < L_; p += 256) m = fmaxf(m, row[p]);
  #pragma unroll
  for (int mask = 1; mask < 64; mask <<= 1) m = fmaxf(m, __shfl_xor(m, mask, 64));
  if ((t & 63) == 0) red[t >> 6] = m;
  __syncthreads();
  m = fmaxf(fmaxf(red[0], red[1]), fmaxf(red[2], red[3]));
  __syncthreads();
  float sum = 0.f;
  for (int p = t; p < L_; p += 256) sum += __expf(row[p] - m);
  #pragma unroll
  for (int mask = 1; mask < 64; mask <<= 1) sum += __shfl_xor(sum, mask, 64);
  if ((t & 63) == 0) red[t >> 6] = sum;
  __syncthreads();
  if (t == 0) {
    wred[br * 2] = m;
    wred[br * 2 + 1] = red[0] + red[1] + red[2] + red[3];
  }
}

// ---------------- Kernel 5: weighted combine over rounds ---------------------
__global__ __launch_bounds__(256) void combine_kernel(
    const unsigned short* __restrict__ att, const float* __restrict__ lse_s,
    const float* __restrict__ wred, float* __restrict__ out) {
  int idx = blockIdx.x * 256 + threadIdx.x;
  int dq = idx & 3;
  int l = (idx >> 2) & (L_ - 1);
  int b = idx >> 14;
  float wv[4];
  #pragma unroll
  for (int r = 0; r < R_; ++r) {
    float m = wred[(b * R_ + r) * 2];
    float sinv = 1.0f / wred[(b * R_ + r) * 2 + 1];
    wv[r] = __expf(lse_s[((size_t)b * R_ + r) * L_ + l] - m) * sinv;
  }
  #pragma unroll
  for (int u = 0; u < 4; ++u) {
    int d4 = dq * 4 + u;
    float4 o = make_float4(0.f, 0.f, 0.f, 0.f);
    #pragma unroll
    for (int r = 0; r < R_; ++r) {
      ushort4 a = *(const ushort4*)(att + ((((size_t)b * R_ + r) * L_ + l) * 16 + d4) * 4);
      o.x += wv[r] * bf2f(a.x); o.y += wv[r] * bf2f(a.y);
      o.z += wv[r] * bf2f(a.z); o.w += wv[r] * bf2f(a.w);
    }
    ((float4*)out)[((size_t)b * L_ + l) * 16 + d4] = o;
  }
}

extern "C" void kernel_launch(void* const* d_in, const int* in_sizes, int n_in,
                              void* d_out, int out_size, void* d_ws, size_t ws_size,
                              hipStream_t stream) {
  const float* query = (const float*)d_in[0];
  const float* value = (const float*)d_in[1];
  const float* rm    = (const float*)d_in[2];
  (void)in_sizes; (void)n_in; (void)out_size; (void)ws_size;

  char* ws = (char*)d_ws;
  const size_t ATT_BYTES = (size_t)B_ * R_ * L_ * DK_ * 2;  // 32 MiB (bf16)
  const size_t MB = 1048576;
  unsigned short* att        = (unsigned short*)ws;
  int*            bucket     = (int*)(ws + ATT_BYTES);
  int*            sorted_pos = (int*)(ws + ATT_BYTES + 1 * MB);
  unsigned char*  cpack      = (unsigned char*)(ws + ATT_BYTES + 2 * MB);
  float*          lse_s      = (float*)(ws + ATT_BYTES + 3 * MB);
  float*          wred       = (float*)(ws + ATT_BYTES + 4 * MB);
  double*         sinvd      = (double*)(ws + ATT_BYTES + 5 * MB);
  float* out = (float*)d_out;

  prep_kernel<<<B_, 128, 0, stream>>>(rm, sinvd);
  hash_kernel<<<B_ * 64, 256, 0, stream>>>(query, rm, sinvd, bucket);
  sort_kernel<<<B_ * R_, 1024, 0, stream>>>(bucket, sorted_pos, cpack);
  attn_kernel<<<B_ * R_ * NB_, 256, 0, stream>>>(query, value, sorted_pos, bucket,
                                                 (const int*)cpack, att, lse_s);
  lsered_kernel<<<B_ * R_, 256, 0, stream>>>(lse_s, wred);
  combine_kernel<<<(B_ * L_ * 4) / 256, 256, 0, stream>>>(att, lse_s, wred, out);
}